// Round 2
// baseline (1062.770 us; speedup 1.0000x reference)
//
#include <hip/hip_runtime.h>
#include <math.h>

typedef unsigned short u16;
typedef __bf16 bf16x8 __attribute__((ext_vector_type(8)));
typedef float f32x4 __attribute__((ext_vector_type(4)));
typedef unsigned short u16x4 __attribute__((ext_vector_type(4)));
typedef unsigned short u16x8 __attribute__((ext_vector_type(8)));

#define DEV static __device__ __forceinline__

DEV float bf2f(u16 u) { union { unsigned int i; float f; } x; x.i = ((unsigned int)u) << 16; return x.f; }
DEV u16 f2bf(float f) { union { float f; unsigned int i; } x; x.f = f; unsigned int r = x.i + 0x7fffu + ((x.i >> 16) & 1u); return (u16)(r >> 16); }

DEV void load_lds16(const void* g, void* l) {
  __builtin_amdgcn_global_load_lds((__attribute__((address_space(1))) void*)g,
                                   (__attribute__((address_space(3))) void*)l, 16, 0, 0);
}

// ---------------------------------------------------------------------------
// Generic NT GEMM: C[m,n] = sum_k A[m,k] * B[n,k], bf16 in, f32 accum.
// 128x128 tile, BK=64, 4 waves (2x2 of 64x64), MFMA 16x16x32.
// XOR swizzle on global source + ds_read (linear global_load_lds dest).
// Batch via grid.z (bz): offset (bz>>4)*s_b + (bz&15)*s_h.
// Optional deterministic split-K: if ksplit>1, grid.y indexes the K-slice
// (m0 forced 0) and C is offset by ks*sKs (use EPI 6, f32 partials).
// EPI: 0 bf16 store | 1 elu+1 bf16 | 2 *aux0[row] bf16 | 3 f32 v+aux0[col]+aux1
//      4 bias+gelu bf16 | 5 f32 += v | 6 f32 store
// ---------------------------------------------------------------------------
template<int EPI>
__global__ __launch_bounds__(256, 2)
void gemm_nt(const u16* __restrict__ A, const u16* __restrict__ B, void* __restrict__ Cv,
             const float* __restrict__ aux0, const float* __restrict__ aux1,
             int M, int N, int K, int lda, int ldb, int ldc,
             long sAb, long sAh, long sBb, long sBh, long sCb, long sCh,
             int ksplit, long sKs)
{
  __shared__ __align__(16) unsigned char smem[32768];
  const int tid = threadIdx.x;
  const int bz = blockIdx.z;
  const long ob = bz >> 4, oh = bz & 15;
  const u16* Ab = A + ob * sAb + oh * sAh;
  const u16* Bb = B + ob * sBb + oh * sBh;
  int mt = blockIdx.y, ks = 0;
  if (ksplit > 1) { ks = blockIdx.y; mt = 0; }
  const long cOff = ob * sCb + oh * sCh + (long)ks * sKs;
  const int m0 = mt * 128, n0 = blockIdx.x * 128;
  const int kchunk = K / ksplit;
  const int klo = ks * kchunk, khi = klo + kchunk;
  const int wid = tid >> 6, lane = tid & 63;
  const int wr = wid >> 1, wc = wid & 1;
  const int ln15 = lane & 15, lq = lane >> 4;
  const int srow = tid >> 3, sch = tid & 7;

  f32x4 acc[4][4] = {};

  for (int k0 = klo; k0 < khi; k0 += 64) {
#pragma unroll
    for (int i = 0; i < 4; ++i) {
      int r = i * 32 + srow;
      int gr = m0 + r; gr = gr < M ? gr : M - 1;
      const unsigned char* src = (const unsigned char*)(Ab + (size_t)gr * lda + k0) + ((sch ^ (r & 7)) << 4);
      unsigned char* dst = smem + r * 128 + (sch << 4);
      load_lds16(src, dst);
    }
#pragma unroll
    for (int i = 0; i < 4; ++i) {
      int r = i * 32 + srow;
      int gc = n0 + r; gc = gc < N ? gc : N - 1;
      const unsigned char* src = (const unsigned char*)(Bb + (size_t)gc * ldb + k0) + ((sch ^ (r & 7)) << 4);
      unsigned char* dst = smem + 16384 + r * 128 + (sch << 4);
      load_lds16(src, dst);
    }
    __syncthreads();
#pragma unroll
    for (int kk = 0; kk < 2; ++kk) {
      bf16x8 af[4], bfv[4];
#pragma unroll
      for (int m = 0; m < 4; ++m) {
        int r = wr * 64 + m * 16 + ln15;
        int kc = kk * 4 + lq;
        af[m] = *(const bf16x8*)(smem + r * 128 + ((kc ^ (r & 7)) << 4));
      }
#pragma unroll
      for (int n = 0; n < 4; ++n) {
        int r = wc * 64 + n * 16 + ln15;
        int kc = kk * 4 + lq;
        bfv[n] = *(const bf16x8*)(smem + 16384 + r * 128 + ((kc ^ (r & 7)) << 4));
      }
#pragma unroll
      for (int m = 0; m < 4; ++m)
#pragma unroll
        for (int n = 0; n < 4; ++n)
          acc[m][n] = __builtin_amdgcn_mfma_f32_16x16x32_bf16(af[m], bfv[n], acc[m][n], 0, 0, 0);
    }
    __syncthreads();
  }

#pragma unroll
  for (int m = 0; m < 4; ++m) {
#pragma unroll
    for (int n = 0; n < 4; ++n) {
      int col = n0 + wc * 64 + n * 16 + ln15;
      if (col >= N) continue;
#pragma unroll
      for (int j = 0; j < 4; ++j) {
        int row = m0 + wr * 64 + m * 16 + lq * 4 + j;
        if (row >= M) continue;
        float v = acc[m][n][j];
        size_t idx = cOff + (size_t)row * ldc + col;
        if (EPI == 0) {
          ((u16*)Cv)[idx] = f2bf(v);
        } else if (EPI == 1) {
          float o = v > 0.f ? v + 1.f : __expf(v);
          ((u16*)Cv)[idx] = f2bf(o);
        } else if (EPI == 2) {
          float o = v * aux0[(size_t)bz * M + row];
          ((u16*)Cv)[idx] = f2bf(o);
        } else if (EPI == 3) {
          ((float*)Cv)[idx] = v + aux0[col] + aux1[(size_t)row * ldc + col];
        } else if (EPI == 4) {
          float g = v + aux0[col];
          float o = 0.5f * g * (1.f + erff(g * 0.70710678118f));
          ((u16*)Cv)[idx] = f2bf(o);
        } else if (EPI == 5) {
          ((float*)Cv)[idx] += v;
        } else if (EPI == 6) {
          ((float*)Cv)[idx] = v;
        }
      }
    }
  }
}

// f32 -> bf16 cast, 4 elems/thread
__global__ __launch_bounds__(256) void cast_kernel(const float* __restrict__ in, u16* __restrict__ out, int n4)
{
  int i = blockIdx.x * 256 + threadIdx.x;
  if (i >= n4) return;
  float4 v = ((const float4*)in)[i];
  u16x4 o = { f2bf(v.x), f2bf(v.y), f2bf(v.z), f2bf(v.w) };
  ((u16x4*)out)[i] = o;
}

// proj (H,HD,F) f32 -> projT (H,F,HD) bf16
__global__ __launch_bounds__(256) void projt_kernel(const float* __restrict__ proj, u16* __restrict__ out)
{
  int i = blockIdx.x * 256 + threadIdx.x;   // 262144 total
  int d = i & 63, f = (i >> 6) & 255, h = i >> 14;
  out[i] = f2bf(proj[((size_t)h * 64 + d) * 256 + f]);
}

// v slice of qkv (b,n,h*64) -> vT (b,h,d,n), 64x64 tiles via LDS
__global__ __launch_bounds__(256) void vt_kernel(const u16* __restrict__ qkv, u16* __restrict__ vT)
{
  __shared__ u16 tile[64][80];
  const int bh = blockIdx.y, b = bh >> 4, h = bh & 15;
  const int n0 = blockIdx.x * 64;
  const int t = threadIdx.x;
  const u16* src = qkv + ((size_t)(b * 4096 + n0)) * 3072 + 2048 + h * 64;
  int r = t >> 2, c = (t & 3) * 16;
  const u16x8* s = (const u16x8*)(src + (size_t)r * 3072 + c);
  *(u16x8*)&tile[r][c] = s[0];
  *(u16x8*)&tile[r][c + 8] = s[1];
  __syncthreads();
  int d = t >> 2, c2 = (t & 3) * 16;
  u16 buf[16];
#pragma unroll
  for (int j = 0; j < 16; ++j) buf[j] = tile[c2 + j][d];
  u16* dstp = vT + ((size_t)bh * 64 + d) * 4096 + n0 + c2;
  *(u16x8*)dstp = *(u16x8*)&buf[0];
  *(u16x8*)(dstp + 8) = *(u16x8*)&buf[8];
}

// ksum[row] = sum over 4096 cols of kfT[row,:], 1 wave/row (row local to group)
__global__ __launch_bounds__(256) void ksum_kernel(const u16* __restrict__ kfT, float* __restrict__ ksum)
{
  int row = blockIdx.x * 4 + (threadIdx.x >> 6);
  int lane = threadIdx.x & 63;
  const u16* p = kfT + (size_t)row * 4096;
  float s = 0.f;
  for (int i = lane; i < 512; i += 64) {
    u16x8 v = ((const u16x8*)p)[i];
#pragma unroll
    for (int j = 0; j < 8; ++j) s += bf2f(v[j]);
  }
  for (int off = 32; off; off >>= 1) s += __shfl_down(s, off);
  if (!lane) ksum[row] = s;
}

// z[row] = 1/(dot(qf[row,:256], ksum[bh_local,:]) + eps), 1 wave/row
__global__ __launch_bounds__(256) void z_kernel(const u16* __restrict__ qf, const float* __restrict__ ksum, float* __restrict__ z)
{
  int row = blockIdx.x * 4 + (threadIdx.x >> 6);
  int lane = threadIdx.x & 63;
  int bh = row >> 12;
  u16x4 v = ((const u16x4*)(qf + (size_t)row * 256))[lane];
  float4 k = ((const float4*)(ksum + (size_t)bh * 256))[lane];
  float s = bf2f(v[0]) * k.x + bf2f(v[1]) * k.y + bf2f(v[2]) * k.z + bf2f(v[3]) * k.w;
  for (int off = 32; off; off >>= 1) s += __shfl_down(s, off);
  if (!lane) z[row] = 1.f / (s + 1e-8f);
}

// sum 8 f32 split-K partials -> bf16
__global__ __launch_bounds__(256) void kvreduce_kernel(const float* __restrict__ part, u16* __restrict__ out)
{
  int i = blockIdx.x * 256 + threadIdx.x;   // 262144
  float s = 0.f;
#pragma unroll
  for (int ks = 0; ks < 8; ++ks) s += part[(size_t)ks * 262144 + i];
  out[i] = f2bf(s);
}

// LayerNorm over 1024 f32, one block/row; optional bf16 copy. In-place safe.
__global__ __launch_bounds__(256) void ln_kernel(const float* __restrict__ in, const float* __restrict__ gamma,
                                                 const float* __restrict__ beta, float* __restrict__ outF,
                                                 u16* __restrict__ outB)
{
  int row = blockIdx.x, tid = threadIdx.x;
  float4 v = ((const float4*)(in + (size_t)row * 1024))[tid];
  float s = v.x + v.y + v.z + v.w;
  float q = v.x * v.x + v.y * v.y + v.z * v.z + v.w * v.w;
  for (int off = 32; off; off >>= 1) { s += __shfl_down(s, off); q += __shfl_down(q, off); }
  __shared__ float rs[4], rq[4];
  int wid = tid >> 6, lane = tid & 63;
  if (!lane) { rs[wid] = s; rq[wid] = q; }
  __syncthreads();
  s = rs[0] + rs[1] + rs[2] + rs[3];
  q = rq[0] + rq[1] + rq[2] + rq[3];
  float mu = s * (1.f / 1024.f);
  float rstd = rsqrtf(q * (1.f / 1024.f) - mu * mu + 1e-5f);
  float4 g = ((const float4*)gamma)[tid];
  float4 bb = ((const float4*)beta)[tid];
  float4 o;
  o.x = (v.x - mu) * rstd * g.x + bb.x;
  o.y = (v.y - mu) * rstd * g.y + bb.y;
  o.z = (v.z - mu) * rstd * g.z + bb.z;
  o.w = (v.w - mu) * rstd * g.w + bb.w;
  ((float4*)(outF + (size_t)row * 1024))[tid] = o;
  if (outB) {
    u16x4 ob = { f2bf(o.x), f2bf(o.y), f2bf(o.z), f2bf(o.w) };
    ((u16x4*)(outB + (size_t)row * 1024))[tid] = ob;
  }
}

// ---------------------------------------------------------------------------
// Workspace layout (bytes), peak 205 MB. d_out doubles as scratch:
//   d_out[0 .. 33.5MB)   : xb (bf16 x), then vT (b,h,d,n)  [dead before outproj]
//   d_out[33.5 .. 67MB)  : kfT group buffer                 [dead before outproj]
// x1 (f32) lives in d_out in place between LN1 and y2 (per-element RMW safe).
// ---------------------------------------------------------------------------
#define O_WQKVB   0L
#define O_WOUTB   6291456L
#define O_W1B     8388608L
#define O_W2B     16777216L
#define O_PROJT   25165824L
#define O_KSUM    25690112L
#define O_Z       25755648L
#define O_KVB     26804224L
#define O_KVP     28901376L
#define O_QFG     37289984L    /* later: x1b */
#define O_QKVB    70844416L    /* later: hb half (67MB) */
#define O_ATTNB   171507712L
#define WS_NEED   205062144L

extern "C" void kernel_launch(void* const* d_in, const int* in_sizes, int n_in,
                              void* d_out, int out_size, void* d_ws, size_t ws_size,
                              hipStream_t stream)
{
  if (ws_size < (size_t)WS_NEED) return;  // signature: clean absmax fail, no fault

  const float* x     = (const float*)d_in[0];
  const float* proj  = (const float*)d_in[1];
  const float* wqkv  = (const float*)d_in[2];
  const float* wout  = (const float*)d_in[3];
  const float* bout  = (const float*)d_in[4];
  const float* gamma = (const float*)d_in[5];
  const float* beta  = (const float*)d_in[6];
  const float* w1    = (const float*)d_in[7];
  const float* b1    = (const float*)d_in[8];
  const float* w2    = (const float*)d_in[9];
  const float* b2    = (const float*)d_in[10];
  float* outp = (float*)d_out;
  char* ws = (char*)d_ws;

  u16* wqkvb  = (u16*)(ws + O_WQKVB);
  u16* woutb  = (u16*)(ws + O_WOUTB);
  u16* w1b    = (u16*)(ws + O_W1B);
  u16* w2b    = (u16*)(ws + O_W2B);
  u16* projTb = (u16*)(ws + O_PROJT);
  float* ksumf= (float*)(ws + O_KSUM);
  float* zf   = (float*)(ws + O_Z);
  u16* kvbB   = (u16*)(ws + O_KVB);
  float* kvpf = (float*)(ws + O_KVP);
  u16* qfG    = (u16*)(ws + O_QFG);
  u16* qkvb   = (u16*)(ws + O_QKVB);
  u16* attnb  = (u16*)(ws + O_ATTNB);
  u16* x1b    = (u16*)(ws + O_QFG);    // reuse (qfG dead)
  u16* hbu    = (u16*)(ws + O_QKVB);   // reuse (qkvb dead), 67MB per half

  u16* xbD  = (u16*)d_out;                       // low 33.5MB
  u16* vTD  = (u16*)d_out;                       // low 33.5MB (after xb dead)
  u16* kfTD = (u16*)((char*)d_out + 33554432L);  // high 33.5MB

  // ---- input casts ----
  cast_kernel<<<16384, 256, 0, stream>>>(x, xbD, 4194304);
  cast_kernel<<<3072, 256, 0, stream>>>(wqkv, wqkvb, 786432);
  cast_kernel<<<1024, 256, 0, stream>>>(wout, woutb, 262144);
  cast_kernel<<<4096, 256, 0, stream>>>(w1, w1b, 1048576);
  cast_kernel<<<4096, 256, 0, stream>>>(w2, w2b, 1048576);
  projt_kernel<<<1024, 256, 0, stream>>>(proj, projTb);

  // ---- qkv = x @ w_qkv^T : (16384x1024)x(3072x1024)^T ----
  gemm_nt<0><<<dim3(24, 128, 1), 256, 0, stream>>>(xbD, wqkvb, qkvb, nullptr, nullptr,
      16384, 3072, 1024, 1024, 1024, 3072, 0L, 0L, 0L, 0L, 0L, 0L, 1, 0L);

  // ---- vT (b,h,d,n) into d_out low half (overwrites xb, now dead) ----
  vt_kernel<<<dim3(64, 64), 256, 0, stream>>>(qkvb, vTD);

  // ---- per-batch groups: 16 heads each ----
  for (int g = 0; g < 4; ++g) {
    const long qkvOff = (long)g * 12582912L;
    // kfT[f,n] = elu(projT @ k^T)+1 : M=256,N=4096,K=64 per head
    gemm_nt<1><<<dim3(32, 2, 16), 256, 0, stream>>>(projTb, qkvb + 1024 + qkvOff, kfTD,
        nullptr, nullptr, 256, 4096, 64, 64, 3072, 4096,
        0L, 16384L, 0L, 64L, 0L, 1048576L, 1, 0L);
    // ksum over n
    ksum_kernel<<<1024, 256, 0, stream>>>(kfTD, ksumf + g * 4096);
    // kv partials: kvT[d,f] = vT @ kfT^T, split-K=8 (f32 partials)
    gemm_nt<6><<<dim3(2, 8, 16), 256, 0, stream>>>(vTD + (long)g * 4194304L, kfTD, kvpf,
        nullptr, nullptr, 64, 256, 4096, 4096, 4096, 256,
        0L, 262144L, 0L, 1048576L, 0L, 16384L, 8, 262144L);
    kvreduce_kernel<<<1024, 256, 0, stream>>>(kvpf, kvbB + (long)g * 262144L);
    // qf = elu(q @ projT^T)+1 : M=4096,N=256,K=64 per head
    gemm_nt<1><<<dim3(2, 32, 16), 256, 0, stream>>>(qkvb + qkvOff, projTb, qfG,
        nullptr, nullptr, 4096, 256, 64, 3072, 64, 256,
        0L, 64L, 0L, 16384L, 0L, 1048576L, 1, 0L);
    // z
    z_kernel<<<16384, 256, 0, stream>>>(qfG, ksumf + g * 4096, zf + g * 65536);
    // attn[n,d] = (qf @ kvT^T)*z -> attnb (b,n,h,d)
    gemm_nt<2><<<dim3(1, 32, 16), 256, 0, stream>>>(qfG, kvbB + (long)g * 262144L,
        attnb + (long)g * 4194304L, zf + g * 65536, nullptr,
        4096, 64, 256, 256, 256, 1024,
        0L, 1048576L, 0L, 16384L, 0L, 64L, 1, 0L);
  }

  // ---- t = x + attn @ w_out^T + b_out (f32 into d_out; vT/kfT dead) ----
  gemm_nt<3><<<dim3(8, 128, 1), 256, 0, stream>>>(attnb, woutb, outp, bout, x,
      16384, 1024, 1024, 1024, 1024, 1024, 0L, 0L, 0L, 0L, 0L, 0L, 1, 0L);

  // ---- x1 = LN(t): f32 in-place in d_out + bf16 copy ----
  ln_kernel<<<16384, 256, 0, stream>>>(outp, gamma, beta, outp, x1b);

  // ---- MLP in two halves of the hidden dim (h fits in 67MB) ----
  for (int half = 0; half < 2; ++half) {
    // h = gelu(x1 @ w1_half^T + b1_half): M=16384,N=2048,K=1024
    gemm_nt<4><<<dim3(16, 128, 1), 256, 0, stream>>>(x1b, w1b + (long)half * 2097152L, hbu,
        b1 + half * 2048, nullptr, 16384, 2048, 1024, 1024, 1024, 2048,
        0L, 0L, 0L, 0L, 0L, 0L, 1, 0L);
    if (half == 0) {
      // y = partial + b2 + x1 (x1 read in-place from d_out)
      gemm_nt<3><<<dim3(8, 128, 1), 256, 0, stream>>>(hbu, w2b + 0L, outp, b2, outp,
          16384, 1024, 2048, 2048, 4096, 1024, 0L, 0L, 0L, 0L, 0L, 0L, 1, 0L);
    } else {
      // y += partial2
      gemm_nt<5><<<dim3(8, 128, 1), 256, 0, stream>>>(hbu, w2b + 2048L, outp, nullptr, nullptr,
          16384, 1024, 2048, 2048, 4096, 1024, 0L, 0L, 0L, 0L, 0L, 0L, 1, 0L);
    }
  }

  // ---- final LN in-place on d_out ----
  ln_kernel<<<16384, 256, 0, stream>>>(outp, gamma, beta, outp, nullptr);
}

// Round 3
// 920.332 us; speedup vs baseline: 1.1548x; 1.1548x over previous
//
#include <hip/hip_runtime.h>
#include <math.h>

typedef unsigned short u16;
typedef __bf16 bf16x8 __attribute__((ext_vector_type(8)));
typedef float f32x4 __attribute__((ext_vector_type(4)));
typedef unsigned short u16x4 __attribute__((ext_vector_type(4)));
typedef unsigned short u16x8 __attribute__((ext_vector_type(8)));

#define DEV static __device__ __forceinline__

DEV float bf2f(u16 u) { union { unsigned int i; float f; } x; x.i = ((unsigned int)u) << 16; return x.f; }
DEV u16 f2bf(float f) { union { float f; unsigned int i; } x; x.f = f; unsigned int r = x.i + 0x7fffu + ((x.i >> 16) & 1u); return (u16)(r >> 16); }

DEV void load_lds16(const void* g, void* l) {
  __builtin_amdgcn_global_load_lds((__attribute__((address_space(1))) void*)g,
                                   (__attribute__((address_space(3))) void*)l, 16, 0, 0);
}

// ---------------------------------------------------------------------------
// Generic NT GEMM: C[m,n] = sum_k A[m,k]*B[n,k], bf16 in, f32 accum.
// 128x128 tile, BK=64, 4 waves, MFMA 16x16x32. XOR swizzle both-sides.
// T1 XCD block swizzle when non-batched, non-splitK, nwg%8==0.
// EPI: 0 bf16 | 3 f32 v+aux0[col]+aux1 | 4 bias+gelu bf16 | 5 f32 += | 6 f32
// ---------------------------------------------------------------------------
template<int EPI>
__global__ __launch_bounds__(256, 2)
void gemm_nt(const u16* __restrict__ A, const u16* __restrict__ B, void* __restrict__ Cv,
             const float* __restrict__ aux0, const float* __restrict__ aux1,
             int M, int N, int K, int lda, int ldb, int ldc,
             long sAb, long sAh, long sBb, long sBh, long sCb, long sCh,
             int ksplit, long sKs)
{
  __shared__ __align__(16) unsigned char smem[32768];
  const int tid = threadIdx.x;
  const int bz = blockIdx.z;
  const long ob = bz >> 4, oh = bz & 15;
  const u16* Ab = A + ob * sAb + oh * sAh;
  const u16* Bb = B + ob * sBb + oh * sBh;
  int bx = blockIdx.x, by = blockIdx.y;
  if (ksplit == 1 && gridDim.z == 1) {
    int nwg = gridDim.x * gridDim.y;
    if ((nwg & 7) == 0) {
      int wg = by * gridDim.x + bx;
      int swz = (wg & 7) * (nwg >> 3) + (wg >> 3);
      bx = swz % gridDim.x; by = swz / gridDim.x;
    }
  }
  int mt = by, ks = 0;
  if (ksplit > 1) { ks = blockIdx.y; mt = 0; }
  const long cOff = ob * sCb + oh * sCh + (long)ks * sKs;
  const int m0 = mt * 128, n0 = bx * 128;
  const int kchunk = K / ksplit;
  const int klo = ks * kchunk, khi = klo + kchunk;
  const int wid = tid >> 6, lane = tid & 63;
  const int wr = wid >> 1, wc = wid & 1;
  const int ln15 = lane & 15, lq = lane >> 4;
  const int srow = tid >> 3, sch = tid & 7;

  f32x4 acc[4][4] = {};

  for (int k0 = klo; k0 < khi; k0 += 64) {
#pragma unroll
    for (int i = 0; i < 4; ++i) {
      int r = i * 32 + srow;
      int gr = m0 + r; gr = gr < M ? gr : M - 1;
      const unsigned char* src = (const unsigned char*)(Ab + (size_t)gr * lda + k0) + ((sch ^ (r & 7)) << 4);
      load_lds16(src, smem + r * 128 + (sch << 4));
    }
#pragma unroll
    for (int i = 0; i < 4; ++i) {
      int r = i * 32 + srow;
      int gc = n0 + r; gc = gc < N ? gc : N - 1;
      const unsigned char* src = (const unsigned char*)(Bb + (size_t)gc * ldb + k0) + ((sch ^ (r & 7)) << 4);
      load_lds16(src, smem + 16384 + r * 128 + (sch << 4));
    }
    __syncthreads();
#pragma unroll
    for (int kk = 0; kk < 2; ++kk) {
      bf16x8 af[4], bfv[4];
#pragma unroll
      for (int m = 0; m < 4; ++m) {
        int r = wr * 64 + m * 16 + ln15;
        int kc = kk * 4 + lq;
        af[m] = *(const bf16x8*)(smem + r * 128 + ((kc ^ (r & 7)) << 4));
      }
#pragma unroll
      for (int n = 0; n < 4; ++n) {
        int r = wc * 64 + n * 16 + ln15;
        int kc = kk * 4 + lq;
        bfv[n] = *(const bf16x8*)(smem + 16384 + r * 128 + ((kc ^ (r & 7)) << 4));
      }
#pragma unroll
      for (int m = 0; m < 4; ++m)
#pragma unroll
        for (int n = 0; n < 4; ++n)
          acc[m][n] = __builtin_amdgcn_mfma_f32_16x16x32_bf16(af[m], bfv[n], acc[m][n], 0, 0, 0);
    }
    __syncthreads();
  }

#pragma unroll
  for (int m = 0; m < 4; ++m) {
#pragma unroll
    for (int n = 0; n < 4; ++n) {
      int col = n0 + wc * 64 + n * 16 + ln15;
      if (col >= N) continue;
#pragma unroll
      for (int j = 0; j < 4; ++j) {
        int row = m0 + wr * 64 + m * 16 + lq * 4 + j;
        if (row >= M) continue;
        float v = acc[m][n][j];
        size_t idx = cOff + (size_t)row * ldc + col;
        if (EPI == 0) {
          ((u16*)Cv)[idx] = f2bf(v);
        } else if (EPI == 3) {
          ((float*)Cv)[idx] = v + aux0[col] + aux1[(size_t)row * ldc + col];
        } else if (EPI == 4) {
          float g = v + aux0[col];
          float o = 0.5f * g * (1.f + erff(g * 0.70710678118f));
          ((u16*)Cv)[idx] = f2bf(o);
        } else if (EPI == 5) {
          ((float*)Cv)[idx] += v;
        } else if (EPI == 6) {
          ((float*)Cv)[idx] = v;
        }
      }
    }
  }
}

// ---------------------------------------------------------------------------
// fused_kv: per (bh, n-chunk 1024): per 64-n tile: kfT=elu(projT@k^T)+1 (LDS),
// kv[f,d] += kfT@vT^T (f32 reg acc), ksum[f] += row sums. Writes partials.
// ---------------------------------------------------------------------------
__global__ __launch_bounds__(256, 2)
void fused_kv(const u16* __restrict__ qkv, const u16* __restrict__ vT,
              const u16* __restrict__ projT, float* __restrict__ kvpart,
              float* __restrict__ ksumpart)
{
  __shared__ __align__(16) unsigned char projS[32768];
  __shared__ __align__(16) unsigned char ktS[8192];
  __shared__ __align__(16) unsigned char vtS[8192];
  __shared__ __align__(16) unsigned char kfS[32768];
  const int tid = threadIdx.x;
  const int bh = blockIdx.y, chunk = blockIdx.x;
  const int b = bh >> 4, h = bh & 15;
  const int wid = tid >> 6, lane = tid & 63;
  const int ln15 = lane & 15, lq = lane >> 4;

  const u16* pg = projT + (size_t)h * 16384;
#pragma unroll
  for (int i = 0; i < 8; ++i) {
    int c = i * 256 + tid; int r = c >> 3, ch = c & 7;
    load_lds16((const unsigned char*)(pg + (size_t)r * 64) + ((ch ^ (r & 7)) << 4),
               projS + r * 128 + ch * 16);
  }

  float ksum_r = 0.f;
  f32x4 acc2[4][4] = {};
  const int n0base = chunk * 1024;

  for (int t = 0; t < 16; ++t) {
    int n0 = n0base + t * 64;
    const u16* kg = qkv + ((size_t)b * 4096 + n0) * 3072 + 1024 + h * 64;
    const u16* vg = vT + (size_t)bh * 64 * 4096 + n0;
#pragma unroll
    for (int i = 0; i < 2; ++i) {
      int c = i * 256 + tid; int r = c >> 3, ch = c & 7;
      load_lds16((const unsigned char*)(kg + (size_t)r * 3072) + ((ch ^ (r & 7)) << 4),
                 ktS + r * 128 + ch * 16);
      load_lds16((const unsigned char*)(vg + (size_t)r * 4096) + ((ch ^ (r & 7)) << 4),
                 vtS + r * 128 + ch * 16);
    }
    __syncthreads();

    f32x4 a1[4][4] = {};
#pragma unroll
    for (int kk = 0; kk < 2; ++kk) {
      int kc = kk * 4 + lq;
      bf16x8 af[4], bv[4];
#pragma unroll
      for (int m = 0; m < 4; ++m) { int r = wid * 64 + m * 16 + ln15; af[m] = *(const bf16x8*)(projS + r * 128 + ((kc ^ (r & 7)) << 4)); }
#pragma unroll
      for (int n = 0; n < 4; ++n) { int r = n * 16 + ln15; bv[n] = *(const bf16x8*)(ktS + r * 128 + ((kc ^ (r & 7)) << 4)); }
#pragma unroll
      for (int m = 0; m < 4; ++m)
#pragma unroll
        for (int n = 0; n < 4; ++n)
          a1[m][n] = __builtin_amdgcn_mfma_f32_16x16x32_bf16(af[m], bv[n], a1[m][n], 0, 0, 0);
    }
#pragma unroll
    for (int m = 0; m < 4; ++m)
#pragma unroll
      for (int n = 0; n < 4; ++n) {
        int nloc = n * 16 + ln15;
        int c = nloc >> 3, wb = (nloc & 7) * 2;
#pragma unroll
        for (int j = 0; j < 4; ++j) {
          int f = wid * 64 + m * 16 + lq * 4 + j;
          float v = a1[m][n][j];
          float o = v > 0.f ? v + 1.f : __expf(v);
          *(u16*)(kfS + f * 128 + ((c ^ (f & 7)) << 4) + wb) = f2bf(o);
        }
      }
    __syncthreads();

    {
      int f = tid;
      float s = 0.f;
#pragma unroll
      for (int c = 0; c < 8; ++c) {
        u16x8 v = *(const u16x8*)(kfS + f * 128 + ((c ^ (f & 7)) << 4));
#pragma unroll
        for (int j = 0; j < 8; ++j) s += bf2f(v[j]);
      }
      ksum_r += s;
    }
#pragma unroll
    for (int kk = 0; kk < 2; ++kk) {
      int kc = kk * 4 + lq;
      bf16x8 af[4], bv[4];
#pragma unroll
      for (int m = 0; m < 4; ++m) { int r = wid * 64 + m * 16 + ln15; af[m] = *(const bf16x8*)(kfS + r * 128 + ((kc ^ (r & 7)) << 4)); }
#pragma unroll
      for (int n = 0; n < 4; ++n) { int r = n * 16 + ln15; bv[n] = *(const bf16x8*)(vtS + r * 128 + ((kc ^ (r & 7)) << 4)); }
#pragma unroll
      for (int m = 0; m < 4; ++m)
#pragma unroll
        for (int n = 0; n < 4; ++n)
          acc2[m][n] = __builtin_amdgcn_mfma_f32_16x16x32_bf16(af[m], bv[n], acc2[m][n], 0, 0, 0);
    }
    __syncthreads();
  }

  const size_t pbase = ((size_t)bh * 4 + chunk) * 16384;
#pragma unroll
  for (int m = 0; m < 4; ++m)
#pragma unroll
    for (int n = 0; n < 4; ++n)
#pragma unroll
      for (int j = 0; j < 4; ++j) {
        int f = wid * 64 + m * 16 + lq * 4 + j;
        int d = n * 16 + ln15;
        kvpart[pbase + (size_t)f * 64 + d] = acc2[m][n][j];
      }
  ksumpart[((size_t)bh * 4 + chunk) * 256 + tid] = ksum_r;
}

__global__ __launch_bounds__(256) void kv_finalize(const float* __restrict__ kvpart,
    const float* __restrict__ ksumpart, u16* __restrict__ kvT, float* __restrict__ ksum)
{
  int bh = blockIdx.x, tid = threadIdx.x;
  const float* base = kvpart + (size_t)bh * 65536;
  u16* out = kvT + (size_t)bh * 16384;
  for (int i = tid; i < 16384; i += 256) {
    int d = i >> 8, f = i & 255;
    size_t o = (size_t)f * 64 + d;
    float s = base[o] + base[o + 16384] + base[o + 32768] + base[o + 49152];
    out[i] = f2bf(s);
  }
  float s = ksumpart[(size_t)bh * 1024 + tid] + ksumpart[(size_t)bh * 1024 + 256 + tid]
          + ksumpart[(size_t)bh * 1024 + 512 + tid] + ksumpart[(size_t)bh * 1024 + 768 + tid];
  ksum[(size_t)bh * 256 + tid] = s;
}

// ---------------------------------------------------------------------------
// fused_attn: per (bh, 64-n tile): qf=elu(q@projT^T)+1 (LDS), z=1/(qf.ksum+eps),
// attn[n,d]=(qf@kvT^T)*z -> attnb (b,n,h,d). kvT B-frags direct from L2.
// ---------------------------------------------------------------------------
__global__ __launch_bounds__(256, 2)
void fused_attn(const u16* __restrict__ qkv, const u16* __restrict__ projT,
                const u16* __restrict__ kvT, const float* __restrict__ ksum,
                u16* __restrict__ attnb)
{
  __shared__ __align__(16) unsigned char projS[32768];
  __shared__ __align__(16) unsigned char qtS[8192];
  __shared__ __align__(16) unsigned char qfS[32768];
  __shared__ float zpart[64][4];
  __shared__ float zS[64];
  const int tid = threadIdx.x;
  const int bh = blockIdx.y, nt = blockIdx.x;
  const int b = bh >> 4, h = bh & 15;
  const int wid = tid >> 6, lane = tid & 63;
  const int ln15 = lane & 15, lq = lane >> 4;
  const int n0 = nt * 64;

  const u16* pg = projT + (size_t)h * 16384;
#pragma unroll
  for (int i = 0; i < 8; ++i) {
    int c = i * 256 + tid; int r = c >> 3, ch = c & 7;
    load_lds16((const unsigned char*)(pg + (size_t)r * 64) + ((ch ^ (r & 7)) << 4),
               projS + r * 128 + ch * 16);
  }
  const u16* qg = qkv + ((size_t)b * 4096 + n0) * 3072 + h * 64;
#pragma unroll
  for (int i = 0; i < 2; ++i) {
    int c = i * 256 + tid; int r = c >> 3, ch = c & 7;
    load_lds16((const unsigned char*)(qg + (size_t)r * 3072) + ((ch ^ (r & 7)) << 4),
               qtS + r * 128 + ch * 16);
  }
  __syncthreads();

  // MFMA1: qf[n,f]; wave owns f-range [wid*64,+64)
  f32x4 a1[4][4] = {};
#pragma unroll
  for (int kk = 0; kk < 2; ++kk) {
    int kc = kk * 4 + lq;
    bf16x8 af[4], bv[4];
#pragma unroll
    for (int m = 0; m < 4; ++m) { int r = m * 16 + ln15; af[m] = *(const bf16x8*)(qtS + r * 128 + ((kc ^ (r & 7)) << 4)); }
#pragma unroll
    for (int n = 0; n < 4; ++n) { int r = wid * 64 + n * 16 + ln15; bv[n] = *(const bf16x8*)(projS + r * 128 + ((kc ^ (r & 7)) << 4)); }
#pragma unroll
    for (int m = 0; m < 4; ++m)
#pragma unroll
      for (int n = 0; n < 4; ++n)
        a1[m][n] = __builtin_amdgcn_mfma_f32_16x16x32_bf16(af[m], bv[n], a1[m][n], 0, 0, 0);
  }
  // elu+1 -> qfS [n][256], stride 512B, chunk swizzle ^(n&7)
#pragma unroll
  for (int m = 0; m < 4; ++m)
#pragma unroll
    for (int n = 0; n < 4; ++n) {
      int f = wid * 64 + n * 16 + ln15;
      int c = f >> 3, wb = (f & 7) * 2;
#pragma unroll
      for (int j = 0; j < 4; ++j) {
        int row = m * 16 + lq * 4 + j;
        float v = a1[m][n][j];
        float o = v > 0.f ? v + 1.f : __expf(v);
        *(u16*)(qfS + row * 512 + ((c ^ (row & 7)) << 4) + wb) = f2bf(o);
      }
    }
  __syncthreads();

  {
    int n = tid & 63, q = tid >> 6;
    const float* kp = ksum + (size_t)bh * 256;
    float s = 0.f;
#pragma unroll
    for (int c = q * 8; c < q * 8 + 8; ++c) {
      u16x8 v = *(const u16x8*)(qfS + n * 512 + ((c ^ (n & 7)) << 4));
#pragma unroll
      for (int j = 0; j < 8; ++j) s += bf2f(v[j]) * kp[c * 8 + j];
    }
    zpart[n][q] = s;
  }
  __syncthreads();
  if (tid < 64) zS[tid] = 1.f / (zpart[tid][0] + zpart[tid][1] + zpart[tid][2] + zpart[tid][3] + 1e-8f);
  __syncthreads();

  // MFMA2: wave owns n-rows [wid*16,+16); K=256 over f
  f32x4 a2[4] = {};
  const u16* kvg = kvT + (size_t)bh * 16384;
#pragma unroll
  for (int kk = 0; kk < 8; ++kk) {
    int kc = kk * 4 + lq;
    int r = wid * 16 + ln15;
    bf16x8 af = *(const bf16x8*)(qfS + r * 512 + ((kc ^ (r & 7)) << 4));
#pragma unroll
    for (int nf = 0; nf < 4; ++nf) {
      int d = nf * 16 + ln15;
      bf16x8 bv = *(const bf16x8*)(kvg + (size_t)d * 256 + kc * 8);
      a2[nf] = __builtin_amdgcn_mfma_f32_16x16x32_bf16(af, bv, a2[nf], 0, 0, 0);
    }
  }
#pragma unroll
  for (int nf = 0; nf < 4; ++nf)
#pragma unroll
    for (int j = 0; j < 4; ++j) {
      int d = nf * 16 + ln15;
      int n = wid * 16 + lq * 4 + j;
      float v = a2[nf][j] * zS[n];
      attnb[((size_t)b * 4096 + n0 + n) * 1024 + h * 64 + d] = f2bf(v);
    }
}

__global__ __launch_bounds__(256) void cast_kernel(const float* __restrict__ in, u16* __restrict__ out, int n4)
{
  int i = blockIdx.x * 256 + threadIdx.x;
  if (i >= n4) return;
  float4 v = ((const float4*)in)[i];
  u16x4 o = { f2bf(v.x), f2bf(v.y), f2bf(v.z), f2bf(v.w) };
  ((u16x4*)out)[i] = o;
}

__global__ __launch_bounds__(256) void projt_kernel(const float* __restrict__ proj, u16* __restrict__ out)
{
  int i = blockIdx.x * 256 + threadIdx.x;
  int d = i & 63, f = (i >> 6) & 255, h = i >> 14;
  out[i] = f2bf(proj[((size_t)h * 64 + d) * 256 + f]);
}

__global__ __launch_bounds__(256) void vt_kernel(const u16* __restrict__ qkv, u16* __restrict__ vT)
{
  __shared__ u16 tile[64][80];
  const int bh = blockIdx.y, b = bh >> 4, h = bh & 15;
  const int n0 = blockIdx.x * 64;
  const int t = threadIdx.x;
  const u16* src = qkv + ((size_t)(b * 4096 + n0)) * 3072 + 2048 + h * 64;
  int r = t >> 2, c = (t & 3) * 16;
  const u16x8* s = (const u16x8*)(src + (size_t)r * 3072 + c);
  *(u16x8*)&tile[r][c] = s[0];
  *(u16x8*)&tile[r][c + 8] = s[1];
  __syncthreads();
  int d = t >> 2, c2 = (t & 3) * 16;
  u16 buf[16];
#pragma unroll
  for (int j = 0; j < 16; ++j) buf[j] = tile[c2 + j][d];
  u16* dstp = vT + ((size_t)bh * 64 + d) * 4096 + n0 + c2;
  *(u16x8*)dstp = *(u16x8*)&buf[0];
  *(u16x8*)(dstp + 8) = *(u16x8*)&buf[8];
}

__global__ __launch_bounds__(256) void ln_kernel(const float* __restrict__ in, const float* __restrict__ gamma,
                                                 const float* __restrict__ beta, float* __restrict__ outF,
                                                 u16* __restrict__ outB)
{
  int row = blockIdx.x, tid = threadIdx.x;
  float4 v = ((const float4*)(in + (size_t)row * 1024))[tid];
  float s = v.x + v.y + v.z + v.w;
  float q = v.x * v.x + v.y * v.y + v.z * v.z + v.w * v.w;
  for (int off = 32; off; off >>= 1) { s += __shfl_down(s, off); q += __shfl_down(q, off); }
  __shared__ float rs[4], rq[4];
  int wid = tid >> 6, lane = tid & 63;
  if (!lane) { rs[wid] = s; rq[wid] = q; }
  __syncthreads();
  s = rs[0] + rs[1] + rs[2] + rs[3];
  q = rq[0] + rq[1] + rq[2] + rq[3];
  float mu = s * (1.f / 1024.f);
  float rstd = rsqrtf(q * (1.f / 1024.f) - mu * mu + 1e-5f);
  float4 g = ((const float4*)gamma)[tid];
  float4 bb = ((const float4*)beta)[tid];
  float4 o;
  o.x = (v.x - mu) * rstd * g.x + bb.x;
  o.y = (v.y - mu) * rstd * g.y + bb.y;
  o.z = (v.z - mu) * rstd * g.z + bb.z;
  o.w = (v.w - mu) * rstd * g.w + bb.w;
  ((float4*)(outF + (size_t)row * 1024))[tid] = o;
  if (outB) {
    u16x4 ob = { f2bf(o.x), f2bf(o.y), f2bf(o.z), f2bf(o.w) };
    ((u16x4*)(outB + (size_t)row * 1024))[tid] = ob;
  }
}

#define O_WQKVB   0L
#define O_WOUTB   6291456L
#define O_W1B     8388608L
#define O_W2B     16777216L
#define O_PROJT   25165824L
#define O_KSUM    25690112L
#define O_KSP     26804224L
#define O_KVB     27852800L
#define O_QFG     37289984L
#define O_QKVB    70844416L
#define O_ATTNB   171507712L
#define WS_NEED   205062144L

extern "C" void kernel_launch(void* const* d_in, const int* in_sizes, int n_in,
                              void* d_out, int out_size, void* d_ws, size_t ws_size,
                              hipStream_t stream)
{
  if (ws_size < (size_t)WS_NEED) return;

  const float* x     = (const float*)d_in[0];
  const float* proj  = (const float*)d_in[1];
  const float* wqkv  = (const float*)d_in[2];
  const float* wout  = (const float*)d_in[3];
  const float* bout  = (const float*)d_in[4];
  const float* gamma = (const float*)d_in[5];
  const float* beta  = (const float*)d_in[6];
  const float* w1    = (const float*)d_in[7];
  const float* b1    = (const float*)d_in[8];
  const float* w2    = (const float*)d_in[9];
  const float* b2    = (const float*)d_in[10];
  float* outp = (float*)d_out;
  char* ws = (char*)d_ws;

  u16* wqkvb  = (u16*)(ws + O_WQKVB);
  u16* woutb  = (u16*)(ws + O_WOUTB);
  u16* w1b    = (u16*)(ws + O_W1B);
  u16* w2b    = (u16*)(ws + O_W2B);
  u16* projTb = (u16*)(ws + O_PROJT);
  float* ksumf= (float*)(ws + O_KSUM);
  float* ksp  = (float*)(ws + O_KSP);
  u16* kvTb   = (u16*)(ws + O_KVB);
  float* kvp  = (float*)(ws + O_QFG);
  u16* qkvb   = (u16*)(ws + O_QKVB);
  u16* attnb  = (u16*)(ws + O_ATTNB);
  u16* x1b    = (u16*)(ws + O_QFG);
  u16* hbu    = (u16*)(ws + O_QKVB);

  u16* xbD  = (u16*)d_out;
  u16* vTD  = (u16*)d_out;

  cast_kernel<<<16384, 256, 0, stream>>>(x, xbD, 4194304);
  cast_kernel<<<3072, 256, 0, stream>>>(wqkv, wqkvb, 786432);
  cast_kernel<<<1024, 256, 0, stream>>>(wout, woutb, 262144);
  cast_kernel<<<4096, 256, 0, stream>>>(w1, w1b, 1048576);
  cast_kernel<<<4096, 256, 0, stream>>>(w2, w2b, 1048576);
  projt_kernel<<<1024, 256, 0, stream>>>(proj, projTb);

  gemm_nt<0><<<dim3(24, 128, 1), 256, 0, stream>>>(xbD, wqkvb, qkvb, nullptr, nullptr,
      16384, 3072, 1024, 1024, 1024, 3072, 0L, 0L, 0L, 0L, 0L, 0L, 1, 0L);

  vt_kernel<<<dim3(64, 64), 256, 0, stream>>>(qkvb, vTD);

  fused_kv<<<dim3(4, 64), 256, 0, stream>>>(qkvb, vTD, projTb, kvp, ksp);
  kv_finalize<<<64, 256, 0, stream>>>(kvp, ksp, kvTb, ksumf);
  fused_attn<<<dim3(64, 64), 256, 0, stream>>>(qkvb, projTb, kvTb, ksumf, attnb);

  gemm_nt<3><<<dim3(8, 128, 1), 256, 0, stream>>>(attnb, woutb, outp, bout, x,
      16384, 1024, 1024, 1024, 1024, 1024, 0L, 0L, 0L, 0L, 0L, 0L, 1, 0L);

  ln_kernel<<<16384, 256, 0, stream>>>(outp, gamma, beta, outp, x1b);

  for (int half = 0; half < 2; ++half) {
    gemm_nt<4><<<dim3(16, 128, 1), 256, 0, stream>>>(x1b, w1b + (long)half * 2097152L, hbu,
        b1 + half * 2048, nullptr, 16384, 2048, 1024, 1024, 1024, 2048,
        0L, 0L, 0L, 0L, 0L, 0L, 1, 0L);
    if (half == 0) {
      gemm_nt<3><<<dim3(8, 128, 1), 256, 0, stream>>>(hbu, w2b + 0L, outp, b2, outp,
          16384, 1024, 2048, 2048, 4096, 1024, 0L, 0L, 0L, 0L, 0L, 0L, 1, 0L);
    } else {
      gemm_nt<5><<<dim3(8, 128, 1), 256, 0, stream>>>(hbu, w2b + 2048L, outp, nullptr, nullptr,
          16384, 1024, 2048, 2048, 4096, 1024, 0L, 0L, 0L, 0L, 0L, 0L, 1, 0L);
    }
  }

  ln_kernel<<<16384, 256, 0, stream>>>(outp, gamma, beta, outp, nullptr);
}